// Round 5
// baseline (82.439 us; speedup 1.0000x reference)
//
#include <hip/hip_runtime.h>
#include <hip/hip_bf16.h>

#define B_    4096
#define F_    32
#define V_    50000
#define E_    64
#define D1_   256
#define DD_   16
#define L2N_  128
#define KX    3072      // stored X width (emb 2048 | inner 1024)
#define KTOT  7168

typedef __bf16 bf16x8 __attribute__((ext_vector_type(8)));
typedef float  f32x4  __attribute__((ext_vector_type(4)));

__device__ __forceinline__ ushort f2b(float f){
  __bf16 h = (__bf16)f; return __builtin_bit_cast(ushort, h);
}
__device__ __forceinline__ float b2f(ushort u){
  return __uint_as_float(((uint)u) << 16);
}
__device__ __forceinline__ float blo(uint u){ return __uint_as_float(u << 16); }
__device__ __forceinline__ float bhi(uint u){ return __uint_as_float(u & 0xffff0000u); }

// ============ K0: prep (blocks 0..639) + gather (blocks 640..1663) ============
__global__ __launch_bounds__(256) void prep_gather(
    const float* __restrict__ Wz, const float* __restrict__ Wpi,
    const float* __restrict__ Wpo, const float* __restrict__ W1,
    const float* __restrict__ W2,
    const int* __restrict__ sparse, const float* __restrict__ tables,
    ushort* __restrict__ WBb, ushort* __restrict__ W1b, ushort* __restrict__ W2b,
    ushort* __restrict__ Xb, ushort* __restrict__ Sb) {
  int bid = blockIdx.x, t = threadIdx.x;
  if (bid < 640) {
    if (bid < 256) {
      int n = bid;
#pragma unroll
      for (int j = 0; j < 7; ++j) {
        int k4 = (j * 256 + t) * 4;
        float4 v;
        if (k4 < 2048)      v = *(const float4*)&Wz [(size_t)n * 2048 + k4];
        else if (k4 < 3072) v = *(const float4*)&Wpi[(size_t)n * 1024 + (k4 - 2048)];
        else                v = *(const float4*)&Wpo[(size_t)n * 4096 + (k4 - 3072)];
        ushort4 o = make_ushort4(f2b(v.x), f2b(v.y), f2b(v.z), f2b(v.w));
        *(ushort4*)&WBb[(size_t)n * KTOT + k4] = o;
      }
    } else if (bid < 512) {
      int n = bid - 256;
      float v0 = (t < 272) ? W1[(size_t)t * 256 + n] : 0.f;
      W1b[(size_t)n * 288 + t] = f2b(v0);
      if (t < 32) {
        int k2 = 256 + t;
        float v1 = (k2 < 272) ? W1[(size_t)k2 * 256 + n] : 0.f;
        W1b[(size_t)n * 288 + k2] = f2b(v1);
      }
    } else {
      int n = bid - 512;
      W2b[(size_t)n * 256 + t] = f2b(W2[(size_t)t * 128 + n]);
    }
    return;
  }

  // ---------------- gather: 1 wave = 1 sample ----------------
  int w = t >> 6, l = t & 63;
  int b = (bid - 640) * 4 + w;
  int fr = l & 15, q = l >> 4;

  int i0 = sparse[b * F_ + fr];
  int i1 = sparse[b * F_ + 16 + fr];
  const float* r0 = tables + ((size_t)fr * V_ + i0) * 64;
  const float* r1 = tables + ((size_t)(16 + fr) * V_ + i1) * 64;

  float4 v[2][2][2];
#pragma unroll
  for (int ks = 0; ks < 2; ++ks) {
    v[0][ks][0] = *(const float4*)(r0 + ks * 32 + q * 8);
    v[0][ks][1] = *(const float4*)(r0 + ks * 32 + q * 8 + 4);
    v[1][ks][0] = *(const float4*)(r1 + ks * 32 + q * 8);
    v[1][ks][1] = *(const float4*)(r1 + ks * 32 + q * 8 + 4);
  }

  bf16x8 fg[2][2];
#pragma unroll
  for (int rh = 0; rh < 2; ++rh)
#pragma unroll
    for (int ks = 0; ks < 2; ++ks) {
      bf16x8 a;
      a[0] = (__bf16)v[rh][ks][0].x; a[1] = (__bf16)v[rh][ks][0].y;
      a[2] = (__bf16)v[rh][ks][0].z; a[3] = (__bf16)v[rh][ks][0].w;
      a[4] = (__bf16)v[rh][ks][1].x; a[5] = (__bf16)v[rh][ks][1].y;
      a[6] = (__bf16)v[rh][ks][1].z; a[7] = (__bf16)v[rh][ks][1].w;
      fg[rh][ks] = a;
      *(bf16x8*)&Xb[(size_t)b * KX + (rh * 16 + fr) * 64 + ks * 32 + q * 8] = a;
    }

  // s = column sums (fp32 shuffle-reduce), stored bf16
  float sv[2][8];
#pragma unroll
  for (int ks = 0; ks < 2; ++ks) {
    sv[ks][0] = v[0][ks][0].x + v[1][ks][0].x; sv[ks][1] = v[0][ks][0].y + v[1][ks][0].y;
    sv[ks][2] = v[0][ks][0].z + v[1][ks][0].z; sv[ks][3] = v[0][ks][0].w + v[1][ks][0].w;
    sv[ks][4] = v[0][ks][1].x + v[1][ks][1].x; sv[ks][5] = v[0][ks][1].y + v[1][ks][1].y;
    sv[ks][6] = v[0][ks][1].z + v[1][ks][1].z; sv[ks][7] = v[0][ks][1].w + v[1][ks][1].w;
  }
#pragma unroll
  for (int m = 1; m < 16; m <<= 1)
#pragma unroll
    for (int ks = 0; ks < 2; ++ks)
#pragma unroll
      for (int j = 0; j < 8; ++j)
        sv[ks][j] += __shfl_xor(sv[ks][j], m, 64);
  if (fr == 0) {
#pragma unroll
    for (int ks = 0; ks < 2; ++ks) {
      ushort4 o0 = make_ushort4(f2b(sv[ks][0]), f2b(sv[ks][1]), f2b(sv[ks][2]), f2b(sv[ks][3]));
      ushort4 o1 = make_ushort4(f2b(sv[ks][4]), f2b(sv[ks][5]), f2b(sv[ks][6]), f2b(sv[ks][7]));
      *(ushort4*)&Sb[(size_t)b * 64 + ks * 32 + q * 8]     = o0;
      *(ushort4*)&Sb[(size_t)b * 64 + ks * 32 + q * 8 + 4] = o1;
    }
  }

  // gram via MFMA (B-frag == A-frag)
  f32x4 g[2][2] = {};
#pragma unroll
  for (int ks = 0; ks < 2; ++ks)
#pragma unroll
    for (int ri = 0; ri < 2; ++ri)
#pragma unroll
      for (int rj = 0; rj < 2; ++rj)
        g[ri][rj] = __builtin_amdgcn_mfma_f32_16x16x32_bf16(
            fg[ri][ks], fg[rj][ks], g[ri][rj], 0, 0, 0);

#pragma unroll
  for (int ri = 0; ri < 2; ++ri)
#pragma unroll
    for (int rj = 0; rj < 2; ++rj)
#pragma unroll
      for (int r = 0; r < 4; ++r) {
        int rowi = ri * 16 + q * 4 + r;
        int colj = rj * 16 + fr;
        Xb[(size_t)b * KX + 2048 + rowi * 32 + colj] = f2b(g[ri][rj][r]);
      }
}

// ============ K1: barrier-free MFMA GEMM, fragments direct from global ======
// grid 256; XCD map: kc = xcd/2 (B-panel L2-resident), nT pairs of an mT
// adjacent on same XCD (A-slice L2 reuse). 4 waves of 64x64, BM=BN=128.
// 28 steps = 12 X-steps + 16 outer-steps, interleaved 1:1 (VMEM vs VALU mix).
__global__ __launch_bounds__(256, 1) void gemm_l1(
    const ushort* __restrict__ Xb, const ushort* __restrict__ WBb,
    const ushort* __restrict__ Sb, float* __restrict__ Lp) {
  __shared__ ushort Ssl[128 * 18];   // s i-slice (16 cols per kc), pad 18

  int bid = blockIdx.x;
  int xcd = bid & 7, idx = bid >> 3;
  int kc  = xcd >> 1;                     // 0..3, fixed per XCD pair
  int mT  = (xcd & 1) * 16 + (idx >> 1);  // 0..31
  int nT  = idx & 1;
  int bRow = mT * 128, n0 = nT * 128;

  int tid = threadIdx.x, w = tid >> 6, l = tid & 63;
  int wm = (w >> 1) * 64, wn = (w & 1) * 64;
  int fr = l & 15, q = l >> 4;

  // stage the 16 s-columns this kc needs (outer i-range)
#pragma unroll
  for (int r = 0; r < 8; ++r) {
    int p = r * 256 + tid;
    int row = p >> 4, col = p & 15;
    Ssl[row * 18 + col] = Sb[(size_t)(bRow + row) * 64 + kc * 16 + col];
  }
  __syncthreads();

  // per-lane packed s_j (bf16 pairs) + fragment base pointers
  uint4 sregu[4][2];
  const ushort* Ab[4];
  const ushort* Bb[4];
#pragma unroll
  for (int mi = 0; mi < 4; ++mi) {
    int grow = bRow + wm + mi * 16 + fr;
    sregu[mi][0] = *(const uint4*)&Sb[(size_t)grow * 64 + q * 8];
    sregu[mi][1] = *(const uint4*)&Sb[(size_t)grow * 64 + 32 + q * 8];
    Ab[mi] = Xb + (size_t)grow * KX + kc * 768 + q * 8;
  }
#pragma unroll
  for (int ni = 0; ni < 4; ++ni)
    Bb[ni] = WBb + (size_t)(n0 + wn + ni * 16 + fr) * KTOT + q * 8;

  f32x4 acc[4][4] = {};
  bf16x8 afb[2][4][2], bfb[2][4][2];

  auto loadA = [&](int buf, int xt) {
#pragma unroll
    for (int mi = 0; mi < 4; ++mi)
#pragma unroll
      for (int ks = 0; ks < 2; ++ks)
        afb[buf][mi][ks] = *(const bf16x8*)(Ab[mi] + xt * 64 + ks * 32);
  };
  auto loadB = [&](int buf, int bkt) {
#pragma unroll
    for (int ni = 0; ni < 4; ++ni)
#pragma unroll
      for (int ks = 0; ks < 2; ++ks)
        bfb[buf][ni][ks] = *(const bf16x8*)(Bb[ni] + bkt * 64 + ks * 32);
  };

  // prologue: step 0 is X0
  loadA(0, 0);
  loadB(0, kc * 12);

#pragma unroll
  for (int s = 0; s < 28; ++s) {
    const bool isX = (s < 24) && ((s & 1) == 0);
    const int  xt  = s >> 1;
    const int  ou  = (s < 24) ? (s >> 1) : (s - 12);

    // prefetch B for step s+1
    if (s + 1 < 28) {
      const int ns = s + 1;
      const bool nX = (ns < 24) && ((ns & 1) == 0);
      const int nbkt = nX ? (kc * 12 + (ns >> 1))
                          : (48 + kc * 16 + ((ns < 24) ? (ns >> 1) : (ns - 12)));
      loadB(ns & 1, nbkt);
    }
    // prefetch A two steps ahead (at X step t, load X step t+1)
    if (isX && (xt + 1) < 12) loadA((xt + 1) & 1, xt + 1);

    if (isX) {
#pragma unroll
      for (int ks = 0; ks < 2; ++ks)
#pragma unroll
        for (int mi = 0; mi < 4; ++mi)
#pragma unroll
          for (int ni = 0; ni < 4; ++ni)
            acc[mi][ni] = __builtin_amdgcn_mfma_f32_16x16x32_bf16(
                afb[xt & 1][mi][ks], bfb[s & 1][ni][ks], acc[mi][ni], 0, 0, 0);
    } else {
      bf16x8 afs[4][2];
#pragma unroll
      for (int mi = 0; mi < 4; ++mi) {
        float si = b2f(Ssl[(wm + mi * 16 + fr) * 18 + ou]);
#pragma unroll
        for (int ks = 0; ks < 2; ++ks) {
          uint4 uv = sregu[mi][ks];
          bf16x8 a;
          a[0] = (__bf16)(si * blo(uv.x)); a[1] = (__bf16)(si * bhi(uv.x));
          a[2] = (__bf16)(si * blo(uv.y)); a[3] = (__bf16)(si * bhi(uv.y));
          a[4] = (__bf16)(si * blo(uv.z)); a[5] = (__bf16)(si * bhi(uv.z));
          a[6] = (__bf16)(si * blo(uv.w)); a[7] = (__bf16)(si * bhi(uv.w));
          afs[mi][ks] = a;
        }
      }
#pragma unroll
      for (int ks = 0; ks < 2; ++ks)
#pragma unroll
        for (int mi = 0; mi < 4; ++mi)
#pragma unroll
          for (int ni = 0; ni < 4; ++ni)
            acc[mi][ni] = __builtin_amdgcn_mfma_f32_16x16x32_bf16(
                afs[mi][ks], bfb[s & 1][ni][ks], acc[mi][ni], 0, 0, 0);
    }
  }

  // epilogue: plain stores to partial buffer kc
  float* Lpk = Lp + (size_t)kc * (B_ * D1_);
#pragma unroll
  for (int mi = 0; mi < 4; ++mi) {
    int row0 = bRow + wm + mi * 16 + (l >> 4) * 4;
#pragma unroll
    for (int ni = 0; ni < 4; ++ni) {
      int col = n0 + wn + ni * 16 + fr;
#pragma unroll
      for (int r = 0; r < 4; ++r)
        Lpk[(size_t)(row0 + r) * D1_ + col] = acc[mi][ni][r];
    }
  }
}

// ============ K2: fused MLP (sum partials + bias, layer1+layer2+head) ======
__global__ __launch_bounds__(256) void mlp_fused(
    const float* __restrict__ Lp, const float* __restrict__ dense,
    const ushort* __restrict__ W1b, const ushort* __restrict__ W2b,
    const float* __restrict__ bz, const float* __restrict__ bpi,
    const float* __restrict__ bpo, const float* __restrict__ B1v,
    const float* __restrict__ b1, const float* __restrict__ b2,
    const float* __restrict__ W3, const float* __restrict__ b3,
    float* __restrict__ out) {
  __shared__ ushort hs[16 * 264];
  __shared__ ushort h2s[16 * 136];
  __shared__ float bvs[256];
  int b0 = blockIdx.x * 16;
  int tid = threadIdx.x, w = tid >> 6, l = tid & 63;
  int row = l & 15, q = l >> 4;
  int wn = w * 64;

  bvs[tid] = bz[tid] + bpi[tid] + bpo[tid] + B1v[tid];
  __syncthreads();

  f32x4 acc1[4] = {};
  const float* L0  = Lp;
  const float* L1p = Lp + (size_t)B_ * D1_;
  const float* L2p = Lp + (size_t)2 * B_ * D1_;
  const float* L3p = Lp + (size_t)3 * B_ * D1_;
  for (int kt = 0; kt < 9; ++kt) {
    int k0 = kt * 32 + q * 8;
    bf16x8 afr;
    if (kt < 8) {
      size_t base = (size_t)(b0 + row) * D1_ + k0;
      float4 s0 = *(const float4*)&L0[base];
      float4 s1 = *(const float4*)&L0[base + 4];
      float4 u;
      u = *(const float4*)&L1p[base];     s0.x+=u.x; s0.y+=u.y; s0.z+=u.z; s0.w+=u.w;
      u = *(const float4*)&L1p[base + 4]; s1.x+=u.x; s1.y+=u.y; s1.z+=u.z; s1.w+=u.w;
      u = *(const float4*)&L2p[base];     s0.x+=u.x; s0.y+=u.y; s0.z+=u.z; s0.w+=u.w;
      u = *(const float4*)&L2p[base + 4]; s1.x+=u.x; s1.y+=u.y; s1.z+=u.z; s1.w+=u.w;
      u = *(const float4*)&L3p[base];     s0.x+=u.x; s0.y+=u.y; s0.z+=u.z; s0.w+=u.w;
      u = *(const float4*)&L3p[base + 4]; s1.x+=u.x; s1.y+=u.y; s1.z+=u.z; s1.w+=u.w;
      float4 bv0 = *(const float4*)&bvs[k0];
      float4 bv1 = *(const float4*)&bvs[k0 + 4];
      afr[0] = (__bf16)(s0.x + bv0.x); afr[1] = (__bf16)(s0.y + bv0.y);
      afr[2] = (__bf16)(s0.z + bv0.z); afr[3] = (__bf16)(s0.w + bv0.w);
      afr[4] = (__bf16)(s1.x + bv1.x); afr[5] = (__bf16)(s1.y + bv1.y);
      afr[6] = (__bf16)(s1.z + bv1.z); afr[7] = (__bf16)(s1.w + bv1.w);
    } else if (q < 2) {
      float4 u0 = *(const float4*)&dense[(size_t)(b0 + row) * DD_ + q * 8];
      float4 u1 = *(const float4*)&dense[(size_t)(b0 + row) * DD_ + q * 8 + 4];
      afr[0] = (__bf16)u0.x; afr[1] = (__bf16)u0.y; afr[2] = (__bf16)u0.z; afr[3] = (__bf16)u0.w;
      afr[4] = (__bf16)u1.x; afr[5] = (__bf16)u1.y; afr[6] = (__bf16)u1.z; afr[7] = (__bf16)u1.w;
    } else {
      afr = (bf16x8)(__bf16)0.f;
    }
#pragma unroll
    for (int ni = 0; ni < 4; ++ni) {
      bf16x8 bfr = *(const bf16x8*)&W1b[(size_t)(wn + ni * 16 + row) * 288 + k0];
      acc1[ni] = __builtin_amdgcn_mfma_f32_16x16x32_bf16(afr, bfr, acc1[ni], 0, 0, 0);
    }
  }
#pragma unroll
  for (int ni = 0; ni < 4; ++ni) {
    int col = wn + ni * 16 + row;
    float bias = b1[col];
#pragma unroll
    for (int r = 0; r < 4; ++r)
      hs[(q * 4 + r) * 264 + col] = f2b(tanhf(acc1[ni][r] + bias));
  }
  __syncthreads();

  int wn2 = w * 32;
  f32x4 acc2[2] = {};
  for (int kt = 0; kt < 8; ++kt) {
    int k0 = kt * 32 + q * 8;
    bf16x8 afr = *(const bf16x8*)&hs[row * 264 + k0];
#pragma unroll
    for (int ni = 0; ni < 2; ++ni) {
      bf16x8 bfr = *(const bf16x8*)&W2b[(size_t)(wn2 + ni * 16 + row) * 256 + k0];
      acc2[ni] = __builtin_amdgcn_mfma_f32_16x16x32_bf16(afr, bfr, acc2[ni], 0, 0, 0);
    }
  }
#pragma unroll
  for (int ni = 0; ni < 2; ++ni) {
    int col = wn2 + ni * 16 + row;
    float bias = b2[col];
#pragma unroll
    for (int r = 0; r < 4; ++r)
      h2s[(q * 4 + r) * 136 + col] = f2b(tanhf(acc2[ni][r] + bias));
  }
  __syncthreads();

  if (w == 0) {
    int rr = l >> 2, g = l & 3;
    float sum = 0.f;
#pragma unroll
    for (int jj = 0; jj < 32; ++jj) {
      int j = g * 32 + jj;
      sum += b2f(h2s[rr * 136 + j]) * W3[j];
    }
    sum += __shfl_xor(sum, 1, 64);
    sum += __shfl_xor(sum, 2, 64);
    if (g == 0) out[b0 + rr] = sum + b3[0];
  }
}

extern "C" void kernel_launch(void* const* d_in, const int* in_sizes, int n_in,
                              void* d_out, int out_size, void* d_ws, size_t ws_size,
                              hipStream_t stream) {
  const int*   sparse = (const int*)  d_in[0];
  const float* dense  = (const float*)d_in[1];
  const float* tables = (const float*)d_in[2];
  const float* Wz     = (const float*)d_in[3];
  const float* bz     = (const float*)d_in[4];
  const float* Wpi    = (const float*)d_in[5];
  const float* bpi    = (const float*)d_in[6];
  const float* Wpo    = (const float*)d_in[7];
  const float* bpo    = (const float*)d_in[8];
  const float* B1v    = (const float*)d_in[9];
  const float* W1     = (const float*)d_in[10];
  const float* b1     = (const float*)d_in[11];
  const float* W2     = (const float*)d_in[12];
  const float* b2     = (const float*)d_in[13];
  const float* W3     = (const float*)d_in[14];
  const float* b3     = (const float*)d_in[15];
  float* out = (float*)d_out;

  // ws layout (bytes), total ~46.4 MB
  char* ws = (char*)d_ws;
  ushort* Xb  = (ushort*)(ws);               // 4096*3072*2 = 25,165,824
  ushort* WBb = (ushort*)(ws + 25165824);    // 256*7168*2  =  3,670,016
  ushort* W1b = (ushort*)(ws + 28835840);    // 256*288*2   =    147,456
  ushort* W2b = (ushort*)(ws + 28983296);    // 128*256*2   =     65,536
  ushort* Sb  = (ushort*)(ws + 29048832);    // 4096*64*2   =    524,288
  float*  Lp  = (float*) (ws + 29573120);    // 4*4096*256*4= 16,777,216

  prep_gather<<<dim3(1664), dim3(256), 0, stream>>>(
      Wz, Wpi, Wpo, W1, W2, sparse, tables, WBb, W1b, W2b, Xb, Sb);
  gemm_l1    <<<dim3(256),  dim3(256), 0, stream>>>(Xb, WBb, Sb, Lp);
  mlp_fused  <<<dim3(256),  dim3(256), 0, stream>>>(
      Lp, dense, W1b, W2b, bz, bpi, bpo, B1v, b1, b2, W3, b3, out);
}

// Round 6
// 69.303 us; speedup vs baseline: 1.1895x; 1.1895x over previous
//
#include <hip/hip_runtime.h>
#include <hip/hip_bf16.h>

#define B_    4096
#define F_    32
#define V_    50000
#define E_    64
#define D1_   256
#define DD_   16
#define L2N_  128
#define KX    3072      // stored X width (emb 2048 | inner 1024)
#define KTOT  7168
#define NKC   8         // split-K factor

typedef __bf16 bf16x8 __attribute__((ext_vector_type(8)));
typedef float  f32x4  __attribute__((ext_vector_type(4)));

typedef __attribute__((address_space(1))) const void gvoid;
typedef __attribute__((address_space(3))) void svoid;

__device__ __forceinline__ ushort f2b(float f){
  __bf16 h = (__bf16)f; return __builtin_bit_cast(ushort, h);
}
__device__ __forceinline__ float b2f(ushort u){
  return __uint_as_float(((uint)u) << 16);
}
__device__ __forceinline__ float blo(uint u){ return __uint_as_float(u << 16); }
__device__ __forceinline__ float bhi(uint u){ return __uint_as_float(u & 0xffff0000u); }
__device__ __forceinline__ void gload16(const void* g, void* l){
  __builtin_amdgcn_global_load_lds((gvoid*)g, (svoid*)l, 16, 0, 0);
}

// ============ K0: prep (blocks 0..639) + gather (blocks 640..1663) ============
__global__ __launch_bounds__(256) void prep_gather(
    const float* __restrict__ Wz, const float* __restrict__ Wpi,
    const float* __restrict__ Wpo, const float* __restrict__ W1,
    const float* __restrict__ W2,
    const int* __restrict__ sparse, const float* __restrict__ tables,
    ushort* __restrict__ WBb, ushort* __restrict__ W1b, ushort* __restrict__ W2b,
    ushort* __restrict__ Xb, ushort* __restrict__ Sb) {
  int bid = blockIdx.x, t = threadIdx.x;
  if (bid < 640) {
    if (bid < 256) {
      int n = bid;
#pragma unroll
      for (int j = 0; j < 7; ++j) {
        int k4 = (j * 256 + t) * 4;
        float4 v;
        if (k4 < 2048)      v = *(const float4*)&Wz [(size_t)n * 2048 + k4];
        else if (k4 < 3072) v = *(const float4*)&Wpi[(size_t)n * 1024 + (k4 - 2048)];
        else                v = *(const float4*)&Wpo[(size_t)n * 4096 + (k4 - 3072)];
        ushort4 o = make_ushort4(f2b(v.x), f2b(v.y), f2b(v.z), f2b(v.w));
        *(ushort4*)&WBb[(size_t)n * KTOT + k4] = o;
      }
    } else if (bid < 512) {
      int n = bid - 256;
      float v0 = (t < 272) ? W1[(size_t)t * 256 + n] : 0.f;
      W1b[(size_t)n * 288 + t] = f2b(v0);
      if (t < 32) {
        int k2 = 256 + t;
        float v1 = (k2 < 272) ? W1[(size_t)k2 * 256 + n] : 0.f;
        W1b[(size_t)n * 288 + k2] = f2b(v1);
      }
    } else {
      int n = bid - 512;
      W2b[(size_t)n * 256 + t] = f2b(W2[(size_t)t * 128 + n]);
    }
    return;
  }

  // ---------------- gather: 1 wave = 1 sample ----------------
  int w = t >> 6, l = t & 63;
  int b = (bid - 640) * 4 + w;
  int fr = l & 15, q = l >> 4;

  int i0 = sparse[b * F_ + fr];
  int i1 = sparse[b * F_ + 16 + fr];
  const float* r0 = tables + ((size_t)fr * V_ + i0) * 64;
  const float* r1 = tables + ((size_t)(16 + fr) * V_ + i1) * 64;

  float4 v[2][2][2];
#pragma unroll
  for (int ks = 0; ks < 2; ++ks) {
    v[0][ks][0] = *(const float4*)(r0 + ks * 32 + q * 8);
    v[0][ks][1] = *(const float4*)(r0 + ks * 32 + q * 8 + 4);
    v[1][ks][0] = *(const float4*)(r1 + ks * 32 + q * 8);
    v[1][ks][1] = *(const float4*)(r1 + ks * 32 + q * 8 + 4);
  }

  bf16x8 fg[2][2];
#pragma unroll
  for (int rh = 0; rh < 2; ++rh)
#pragma unroll
    for (int ks = 0; ks < 2; ++ks) {
      bf16x8 a;
      a[0] = (__bf16)v[rh][ks][0].x; a[1] = (__bf16)v[rh][ks][0].y;
      a[2] = (__bf16)v[rh][ks][0].z; a[3] = (__bf16)v[rh][ks][0].w;
      a[4] = (__bf16)v[rh][ks][1].x; a[5] = (__bf16)v[rh][ks][1].y;
      a[6] = (__bf16)v[rh][ks][1].z; a[7] = (__bf16)v[rh][ks][1].w;
      fg[rh][ks] = a;
      *(bf16x8*)&Xb[(size_t)b * KX + (rh * 16 + fr) * 64 + ks * 32 + q * 8] = a;
    }

  // s = column sums (fp32 shuffle-reduce), stored bf16
  float sv[2][8];
#pragma unroll
  for (int ks = 0; ks < 2; ++ks) {
    sv[ks][0] = v[0][ks][0].x + v[1][ks][0].x; sv[ks][1] = v[0][ks][0].y + v[1][ks][0].y;
    sv[ks][2] = v[0][ks][0].z + v[1][ks][0].z; sv[ks][3] = v[0][ks][0].w + v[1][ks][0].w;
    sv[ks][4] = v[0][ks][1].x + v[1][ks][1].x; sv[ks][5] = v[0][ks][1].y + v[1][ks][1].y;
    sv[ks][6] = v[0][ks][1].z + v[1][ks][1].z; sv[ks][7] = v[0][ks][1].w + v[1][ks][1].w;
  }
#pragma unroll
  for (int m = 1; m < 16; m <<= 1)
#pragma unroll
    for (int ks = 0; ks < 2; ++ks)
#pragma unroll
      for (int j = 0; j < 8; ++j)
        sv[ks][j] += __shfl_xor(sv[ks][j], m, 64);
  if (fr == 0) {
#pragma unroll
    for (int ks = 0; ks < 2; ++ks) {
      ushort4 o0 = make_ushort4(f2b(sv[ks][0]), f2b(sv[ks][1]), f2b(sv[ks][2]), f2b(sv[ks][3]));
      ushort4 o1 = make_ushort4(f2b(sv[ks][4]), f2b(sv[ks][5]), f2b(sv[ks][6]), f2b(sv[ks][7]));
      *(ushort4*)&Sb[(size_t)b * 64 + ks * 32 + q * 8]     = o0;
      *(ushort4*)&Sb[(size_t)b * 64 + ks * 32 + q * 8 + 4] = o1;
    }
  }

  // gram via MFMA (B-frag == A-frag)
  f32x4 g[2][2] = {};
#pragma unroll
  for (int ks = 0; ks < 2; ++ks)
#pragma unroll
    for (int ri = 0; ri < 2; ++ri)
#pragma unroll
      for (int rj = 0; rj < 2; ++rj)
        g[ri][rj] = __builtin_amdgcn_mfma_f32_16x16x32_bf16(
            fg[ri][ks], fg[rj][ks], g[ri][rj], 0, 0, 0);

#pragma unroll
  for (int ri = 0; ri < 2; ++ri)
#pragma unroll
    for (int rj = 0; rj < 2; ++rj)
#pragma unroll
      for (int r = 0; r < 4; ++r) {
        int rowi = ri * 16 + q * 4 + r;
        int colj = rj * 16 + fr;
        Xb[(size_t)b * KX + 2048 + rowi * 32 + colj] = f2b(g[ri][rj][r]);
      }
}

// ============ K1: MFMA GEMM, BM=128 x BN=256(full), 8-way split-K ============
// grid 256 = 32 mT x 8 kc; bid&7 == kc == XCD -> 458 KB B-slice L2-resident.
// 512 thr = 8 waves of 64x64 -> 2 waves/SIMD (stall overlap). 14 iters/block.
__global__ __launch_bounds__(512, 1) void gemm_l1(
    const ushort* __restrict__ Xb, const ushort* __restrict__ WBb,
    const ushort* __restrict__ Sb, float* __restrict__ Lp) {
  __shared__ __align__(16) ushort As[2][128 * 64];   // 2 x 16 KB
  __shared__ __align__(16) ushort Bs[2][256 * 64];   // 2 x 32 KB
  __shared__ ushort Ssl[128 * 18];                   // 4.6 KB s i-slice

  int bid = blockIdx.x;
  int kc  = bid & 7;           // == XCD id (grid 256 round-robins 8 XCDs)
  int mT  = bid >> 3;          // 0..31
  int bRow = mT * 128;
  int kt0 = kc * 14;
  int i_start = min(max(0, kt0 - 48), 48);

  int tid = threadIdx.x, w = tid >> 6, l = tid & 63;
  int wm = (w >> 2) * 64, wn = (w & 3) * 64;
  int fr = l & 15, q = l >> 4;

  // stage Ssl: 128 rows x 16 s-cols [i_start, i_start+16)
#pragma unroll
  for (int r = 0; r < 2; ++r) {
    int p = r * 1024 + tid * 2;
    int row = p >> 4, col = p & 15;
    *(ushort2*)&Ssl[row * 18 + col] =
        *(const ushort2*)&Sb[(size_t)(bRow + row) * 64 + i_start + col];
  }

  // per-lane packed s_j (bf16 pairs) for outer-fragment synthesis
  uint4 sregu[4][2];
#pragma unroll
  for (int mi = 0; mi < 4; ++mi) {
    int grow = bRow + wm + mi * 16 + fr;
    sregu[mi][0] = *(const uint4*)&Sb[(size_t)grow * 64 + q * 8];
    sregu[mi][1] = *(const uint4*)&Sb[(size_t)grow * 64 + 32 + q * 8];
  }

  int r8 = l >> 3;
  int sg = ((l & 7) ^ r8) * 8;   // inverse-swizzled source slot

  auto stageA = [&](int bI, int kt) {   // 128x64: wave w rows [w*16, w*16+16)
    const ushort* src = Xb + (size_t)(bRow + w * 16 + r8) * KX + kt * 64 + sg;
#pragma unroll
    for (int c = 0; c < 2; ++c)
      gload16(src + (size_t)(c * 8) * KX, &As[bI][(w * 16 + c * 8) * 64]);
  };
  auto stageB = [&](int bI, int kt) {   // 256x64: wave w rows [w*32, w*32+32)
    const ushort* src = WBb + (size_t)(w * 32 + r8) * KTOT + kt * 64 + sg;
#pragma unroll
    for (int c = 0; c < 4; ++c)
      gload16(src + (size_t)(c * 8) * KTOT, &Bs[bI][(w * 32 + c * 8) * 64]);
  };

  f32x4 acc[4][4] = {};
  bf16x8 af[4][2], bfr[4][2];
  int buf = 0;

  if (kt0 < 48) stageA(0, kt0);
  stageB(0, kt0);
  __syncthreads();

#pragma unroll
  for (int tl = 0; tl < 14; ++tl) {
    int kt = kt0 + tl;
    if (tl + 1 < 14) {
      if (kt + 1 < 48) stageA(buf ^ 1, kt + 1);
      stageB(buf ^ 1, kt + 1);
    }

#pragma unroll
    for (int ni = 0; ni < 4; ++ni) {
      int col = wn + ni * 16 + fr;
#pragma unroll
      for (int ks = 0; ks < 2; ++ks) {
        int slot = (ks * 4 + q) ^ (col & 7);
        bfr[ni][ks] = *(const bf16x8*)&Bs[buf][col * 64 + slot * 8];
      }
    }
    if (kt < 48) {            // X region: fragments from LDS
#pragma unroll
      for (int mi = 0; mi < 4; ++mi) {
        int row = wm + mi * 16 + fr;
#pragma unroll
        for (int ks = 0; ks < 2; ++ks) {
          int slot = (ks * 4 + q) ^ (row & 7);
          af[mi][ks] = *(const bf16x8*)&As[buf][row * 64 + slot * 8];
        }
      }
    } else {                  // outer region: A[m][j] = s[m][i] * s[m][j]
      int iloc = kt - 48 - i_start;      // runtime, LDS index only
#pragma unroll
      for (int mi = 0; mi < 4; ++mi) {
        float si = b2f(Ssl[(wm + mi * 16 + fr) * 18 + iloc]);
#pragma unroll
        for (int ks = 0; ks < 2; ++ks) {
          uint4 uv = sregu[mi][ks];
          bf16x8 a;
          a[0] = (__bf16)(si * blo(uv.x)); a[1] = (__bf16)(si * bhi(uv.x));
          a[2] = (__bf16)(si * blo(uv.y)); a[3] = (__bf16)(si * bhi(uv.y));
          a[4] = (__bf16)(si * blo(uv.z)); a[5] = (__bf16)(si * bhi(uv.z));
          a[6] = (__bf16)(si * blo(uv.w)); a[7] = (__bf16)(si * bhi(uv.w));
          af[mi][ks] = a;
        }
      }
    }
#pragma unroll
    for (int ks = 0; ks < 2; ++ks)
#pragma unroll
      for (int mi = 0; mi < 4; ++mi)
#pragma unroll
        for (int ni = 0; ni < 4; ++ni)
          acc[mi][ni] = __builtin_amdgcn_mfma_f32_16x16x32_bf16(
              af[mi][ks], bfr[ni][ks], acc[mi][ni], 0, 0, 0);
    __syncthreads();
    buf ^= 1;
  }

  // epilogue: plain stores to partial buffer kc
  float* Lpk = Lp + (size_t)kc * (B_ * D1_);
#pragma unroll
  for (int mi = 0; mi < 4; ++mi) {
    int row0 = bRow + wm + mi * 16 + q * 4;
#pragma unroll
    for (int ni = 0; ni < 4; ++ni) {
      int col = wn + ni * 16 + fr;
#pragma unroll
      for (int r = 0; r < 4; ++r)
        Lpk[(size_t)(row0 + r) * D1_ + col] = acc[mi][ni][r];
    }
  }
}

// ============ K2: fused MLP (sum 8 partials + bias, layer1+layer2+head) =====
__global__ __launch_bounds__(256) void mlp_fused(
    const float* __restrict__ Lp, const float* __restrict__ dense,
    const ushort* __restrict__ W1b, const ushort* __restrict__ W2b,
    const float* __restrict__ bz, const float* __restrict__ bpi,
    const float* __restrict__ bpo, const float* __restrict__ B1v,
    const float* __restrict__ b1, const float* __restrict__ b2,
    const float* __restrict__ W3, const float* __restrict__ b3,
    float* __restrict__ out) {
  __shared__ ushort hs[16 * 264];
  __shared__ ushort h2s[16 * 136];
  __shared__ float bvs[256];
  int b0 = blockIdx.x * 16;
  int tid = threadIdx.x, w = tid >> 6, l = tid & 63;
  int row = l & 15, q = l >> 4;
  int wn = w * 64;

  bvs[tid] = bz[tid] + bpi[tid] + bpo[tid] + B1v[tid];
  __syncthreads();

  f32x4 acc1[4] = {};
  for (int kt = 0; kt < 9; ++kt) {
    int k0 = kt * 32 + q * 8;
    bf16x8 afr;
    if (kt < 8) {
      size_t base = (size_t)(b0 + row) * D1_ + k0;
      float4 s0 = make_float4(0.f, 0.f, 0.f, 0.f);
      float4 s1 = make_float4(0.f, 0.f, 0.f, 0.f);
#pragma unroll
      for (int p = 0; p < NKC; ++p) {
        const float* Lpp = Lp + (size_t)p * (B_ * D1_);
        float4 u0 = *(const float4*)&Lpp[base];
        float4 u1 = *(const float4*)&Lpp[base + 4];
        s0.x += u0.x; s0.y += u0.y; s0.z += u0.z; s0.w += u0.w;
        s1.x += u1.x; s1.y += u1.y; s1.z += u1.z; s1.w += u1.w;
      }
      float4 bv0 = *(const float4*)&bvs[k0];
      float4 bv1 = *(const float4*)&bvs[k0 + 4];
      afr[0] = (__bf16)(s0.x + bv0.x); afr[1] = (__bf16)(s0.y + bv0.y);
      afr[2] = (__bf16)(s0.z + bv0.z); afr[3] = (__bf16)(s0.w + bv0.w);
      afr[4] = (__bf16)(s1.x + bv1.x); afr[5] = (__bf16)(s1.y + bv1.y);
      afr[6] = (__bf16)(s1.z + bv1.z); afr[7] = (__bf16)(s1.w + bv1.w);
    } else if (q < 2) {
      float4 u0 = *(const float4*)&dense[(size_t)(b0 + row) * DD_ + q * 8];
      float4 u1 = *(const float4*)&dense[(size_t)(b0 + row) * DD_ + q * 8 + 4];
      afr[0] = (__bf16)u0.x; afr[1] = (__bf16)u0.y; afr[2] = (__bf16)u0.z; afr[3] = (__bf16)u0.w;
      afr[4] = (__bf16)u1.x; afr[5] = (__bf16)u1.y; afr[6] = (__bf16)u1.z; afr[7] = (__bf16)u1.w;
    } else {
      afr = (bf16x8)(__bf16)0.f;
    }
#pragma unroll
    for (int ni = 0; ni < 4; ++ni) {
      bf16x8 bfr = *(const bf16x8*)&W1b[(size_t)(wn + ni * 16 + row) * 288 + k0];
      acc1[ni] = __builtin_amdgcn_mfma_f32_16x16x32_bf16(afr, bfr, acc1[ni], 0, 0, 0);
    }
  }
#pragma unroll
  for (int ni = 0; ni < 4; ++ni) {
    int col = wn + ni * 16 + row;
    float bias = b1[col];
#pragma unroll
    for (int r = 0; r < 4; ++r)
      hs[(q * 4 + r) * 264 + col] = f2b(tanhf(acc1[ni][r] + bias));
  }
  __syncthreads();

  int wn2 = w * 32;
  f32x4 acc2[2] = {};
  for (int kt = 0; kt < 8; ++kt) {
    int k0 = kt * 32 + q * 8;
    bf16x8 afr = *(const bf16x8*)&hs[row * 264 + k0];
#pragma unroll
    for (int ni = 0; ni < 2; ++ni) {
      bf16x8 bfr = *(const bf16x8*)&W2b[(size_t)(wn2 + ni * 16 + row) * 256 + k0];
      acc2[ni] = __builtin_amdgcn_mfma_f32_16x16x32_bf16(afr, bfr, acc2[ni], 0, 0, 0);
    }
  }
#pragma unroll
  for (int ni = 0; ni < 2; ++ni) {
    int col = wn2 + ni * 16 + row;
    float bias = b2[col];
#pragma unroll
    for (int r = 0; r < 4; ++r)
      h2s[(q * 4 + r) * 136 + col] = f2b(tanhf(acc2[ni][r] + bias));
  }
  __syncthreads();

  if (w == 0) {
    int rr = l >> 2, g = l & 3;
    float sum = 0.f;
#pragma unroll
    for (int jj = 0; jj < 32; ++jj) {
      int j = g * 32 + jj;
      sum += b2f(h2s[rr * 136 + j]) * W3[j];
    }
    sum += __shfl_xor(sum, 1, 64);
    sum += __shfl_xor(sum, 2, 64);
    if (g == 0) out[b0 + rr] = sum + b3[0];
  }
}

extern "C" void kernel_launch(void* const* d_in, const int* in_sizes, int n_in,
                              void* d_out, int out_size, void* d_ws, size_t ws_size,
                              hipStream_t stream) {
  const int*   sparse = (const int*)  d_in[0];
  const float* dense  = (const float*)d_in[1];
  const float* tables = (const float*)d_in[2];
  const float* Wz     = (const float*)d_in[3];
  const float* bz     = (const float*)d_in[4];
  const float* Wpi    = (const float*)d_in[5];
  const float* bpi    = (const float*)d_in[6];
  const float* Wpo    = (const float*)d_in[7];
  const float* bpo    = (const float*)d_in[8];
  const float* B1v    = (const float*)d_in[9];
  const float* W1     = (const float*)d_in[10];
  const float* b1     = (const float*)d_in[11];
  const float* W2     = (const float*)d_in[12];
  const float* b2     = (const float*)d_in[13];
  const float* W3     = (const float*)d_in[14];
  const float* b3     = (const float*)d_in[15];
  float* out = (float*)d_out;

  // ws layout (bytes), total 63.1 MB (< 64 MiB)
  char* ws = (char*)d_ws;
  ushort* Xb  = (ushort*)(ws);               // 4096*3072*2 = 25,165,824
  ushort* WBb = (ushort*)(ws + 25165824);    // 256*7168*2  =  3,670,016
  ushort* W1b = (ushort*)(ws + 28835840);    // 256*288*2   =    147,456
  ushort* W2b = (ushort*)(ws + 28983296);    // 128*256*2   =     65,536
  ushort* Sb  = (ushort*)(ws + 29048832);    // 4096*64*2   =    524,288
  float*  Lp  = (float*) (ws + 29573120);    // 8*4096*256*4= 33,554,432

  prep_gather<<<dim3(1664), dim3(256), 0, stream>>>(
      Wz, Wpi, Wpo, W1, W2, sparse, tables, WBb, W1b, W2b, Xb, Sb);
  gemm_l1    <<<dim3(256),  dim3(512), 0, stream>>>(Xb, WBb, Sb, Lp);
  mlp_fused  <<<dim3(256),  dim3(256), 0, stream>>>(
      Lp, dense, W1b, W2b, bz, bpi, bpo, B1v, b1, b2, W3, b3, out);
}

// Round 7
// 59.774 us; speedup vs baseline: 1.3792x; 1.1594x over previous
//
#include <hip/hip_runtime.h>
#include <hip/hip_bf16.h>

#define B_    4096
#define F_    32
#define V_    50000
#define E_    64
#define D1_   256
#define DD_   16
#define L2N_  128
#define KX    3072      // stored X width (emb 2048 | inner 1024)
#define KTOT  7168
#define NKC   8         // split-K factor

typedef __bf16 bf16x8 __attribute__((ext_vector_type(8)));
typedef float  f32x4  __attribute__((ext_vector_type(4)));

typedef __attribute__((address_space(1))) const void gvoid;
typedef __attribute__((address_space(3))) void svoid;

__device__ __forceinline__ ushort f2b(float f){
  __bf16 h = (__bf16)f; return __builtin_bit_cast(ushort, h);
}
__device__ __forceinline__ float b2f(ushort u){
  return __uint_as_float(((uint)u) << 16);
}
__device__ __forceinline__ float blo(uint u){ return __uint_as_float(u << 16); }
__device__ __forceinline__ float bhi(uint u){ return __uint_as_float(u & 0xffff0000u); }
__device__ __forceinline__ void gload16(const void* g, void* l){
  __builtin_amdgcn_global_load_lds((gvoid*)g, (svoid*)l, 16, 0, 0);
}

// ============ K0: prep (blocks 0..639) + gather (blocks 640..1663) ============
__global__ __launch_bounds__(256) void prep_gather(
    const float* __restrict__ Wz, const float* __restrict__ Wpi,
    const float* __restrict__ Wpo, const float* __restrict__ W1,
    const float* __restrict__ W2,
    const int* __restrict__ sparse, const float* __restrict__ tables,
    ushort* __restrict__ WBb, ushort* __restrict__ W1b, ushort* __restrict__ W2b,
    ushort* __restrict__ Xb, ushort* __restrict__ Sb) {
  __shared__ ushort gsh[4][32 * 72];   // gram staging, 16B-aligned rows
  int bid = blockIdx.x, t = threadIdx.x;
  if (bid < 640) {
    if (bid < 256) {
      int n = bid;
#pragma unroll
      for (int j = 0; j < 7; ++j) {
        int k4 = (j * 256 + t) * 4;
        float4 v;
        if (k4 < 2048)      v = *(const float4*)&Wz [(size_t)n * 2048 + k4];
        else if (k4 < 3072) v = *(const float4*)&Wpi[(size_t)n * 1024 + (k4 - 2048)];
        else                v = *(const float4*)&Wpo[(size_t)n * 4096 + (k4 - 3072)];
        ushort4 o = make_ushort4(f2b(v.x), f2b(v.y), f2b(v.z), f2b(v.w));
        *(ushort4*)&WBb[(size_t)n * KTOT + k4] = o;
      }
    } else if (bid < 512) {
      int n = bid - 256;
      float v0 = (t < 272) ? W1[(size_t)t * 256 + n] : 0.f;
      W1b[(size_t)n * 288 + t] = f2b(v0);
      if (t < 32) {
        int k2 = 256 + t;
        float v1 = (k2 < 272) ? W1[(size_t)k2 * 256 + n] : 0.f;
        W1b[(size_t)n * 288 + k2] = f2b(v1);
      }
    } else {
      int n = bid - 512;
      W2b[(size_t)n * 256 + t] = f2b(W2[(size_t)t * 128 + n]);
    }
    return;
  }

  // ---------------- gather: 1 wave = 1 sample ----------------
  int w = t >> 6, l = t & 63;
  int b = (bid - 640) * 4 + w;
  int fr = l & 15, q = l >> 4;

  int i0 = sparse[b * F_ + fr];
  int i1 = sparse[b * F_ + 16 + fr];
  const float* r0 = tables + ((size_t)fr * V_ + i0) * 64;
  const float* r1 = tables + ((size_t)(16 + fr) * V_ + i1) * 64;

  float4 v[2][2][2];
#pragma unroll
  for (int ks = 0; ks < 2; ++ks) {
    v[0][ks][0] = *(const float4*)(r0 + ks * 32 + q * 8);
    v[0][ks][1] = *(const float4*)(r0 + ks * 32 + q * 8 + 4);
    v[1][ks][0] = *(const float4*)(r1 + ks * 32 + q * 8);
    v[1][ks][1] = *(const float4*)(r1 + ks * 32 + q * 8 + 4);
  }

  bf16x8 fg[2][2];
#pragma unroll
  for (int rh = 0; rh < 2; ++rh)
#pragma unroll
    for (int ks = 0; ks < 2; ++ks) {
      bf16x8 a;
      a[0] = (__bf16)v[rh][ks][0].x; a[1] = (__bf16)v[rh][ks][0].y;
      a[2] = (__bf16)v[rh][ks][0].z; a[3] = (__bf16)v[rh][ks][0].w;
      a[4] = (__bf16)v[rh][ks][1].x; a[5] = (__bf16)v[rh][ks][1].y;
      a[6] = (__bf16)v[rh][ks][1].z; a[7] = (__bf16)v[rh][ks][1].w;
      fg[rh][ks] = a;
      *(bf16x8*)&Xb[(size_t)b * KX + (rh * 16 + fr) * 64 + ks * 32 + q * 8] = a;
    }

  // s = column sums (fp32 shuffle-reduce), stored bf16
  float sv[2][8];
#pragma unroll
  for (int ks = 0; ks < 2; ++ks) {
    sv[ks][0] = v[0][ks][0].x + v[1][ks][0].x; sv[ks][1] = v[0][ks][0].y + v[1][ks][0].y;
    sv[ks][2] = v[0][ks][0].z + v[1][ks][0].z; sv[ks][3] = v[0][ks][0].w + v[1][ks][0].w;
    sv[ks][4] = v[0][ks][1].x + v[1][ks][1].x; sv[ks][5] = v[0][ks][1].y + v[1][ks][1].y;
    sv[ks][6] = v[0][ks][1].z + v[1][ks][1].z; sv[ks][7] = v[0][ks][1].w + v[1][ks][1].w;
  }
#pragma unroll
  for (int m = 1; m < 16; m <<= 1)
#pragma unroll
    for (int ks = 0; ks < 2; ++ks)
#pragma unroll
      for (int j = 0; j < 8; ++j)
        sv[ks][j] += __shfl_xor(sv[ks][j], m, 64);
  if (fr == 0) {
#pragma unroll
    for (int ks = 0; ks < 2; ++ks) {
      ushort4 o0 = make_ushort4(f2b(sv[ks][0]), f2b(sv[ks][1]), f2b(sv[ks][2]), f2b(sv[ks][3]));
      ushort4 o1 = make_ushort4(f2b(sv[ks][4]), f2b(sv[ks][5]), f2b(sv[ks][6]), f2b(sv[ks][7]));
      *(ushort4*)&Sb[(size_t)b * 64 + ks * 32 + q * 8]     = o0;
      *(ushort4*)&Sb[(size_t)b * 64 + ks * 32 + q * 8 + 4] = o1;
    }
  }

  // gram via MFMA (B-frag == A-frag)
  f32x4 g[2][2] = {};
#pragma unroll
  for (int ks = 0; ks < 2; ++ks)
#pragma unroll
    for (int ri = 0; ri < 2; ++ri)
#pragma unroll
      for (int rj = 0; rj < 2; ++rj)
        g[ri][rj] = __builtin_amdgcn_mfma_f32_16x16x32_bf16(
            fg[ri][ks], fg[rj][ks], g[ri][rj], 0, 0, 0);

  // stage gram in LDS (wave-private), then coalesced 32B/lane global write
#pragma unroll
  for (int ri = 0; ri < 2; ++ri)
#pragma unroll
    for (int rj = 0; rj < 2; ++rj)
#pragma unroll
      for (int r = 0; r < 4; ++r)
        gsh[w][(ri * 16 + q * 4 + r) * 72 + rj * 16 + fr] = f2b(g[ri][rj][r]);
  // wave-private LDS: compiler inserts lgkmcnt wait on the dependent reads
  {
    int rrow = l >> 1, rcol = (l & 1) * 16;
    uint4 ga = *(const uint4*)&gsh[w][rrow * 72 + rcol];
    uint4 gb = *(const uint4*)&gsh[w][rrow * 72 + rcol + 8];
    size_t dst = (size_t)b * KX + 2048 + rrow * 32 + rcol;
    *(uint4*)&Xb[dst]     = ga;
    *(uint4*)&Xb[dst + 8] = gb;
  }
}

// ============ K1: MFMA GEMM, BM=128 x BN=256(full), 8-way split-K ============
// grid 256 = 32 mT x 8 kc; bid&7 == kc == XCD -> 458 KB B-slice L2-resident.
// 512 thr = 8 waves of 64x64 -> 2 waves/SIMD. 14 iters/block. bf16 partials.
__global__ __launch_bounds__(512, 1) void gemm_l1(
    const ushort* __restrict__ Xb, const ushort* __restrict__ WBb,
    const ushort* __restrict__ Sb, ushort* __restrict__ Lp) {
  __shared__ __align__(16) ushort As[2][128 * 64];   // 2 x 16 KB
  __shared__ __align__(16) ushort Bs[2][256 * 64];   // 2 x 32 KB
  __shared__ ushort Ssl[128 * 18];                   // 4.6 KB s i-slice

  int bid = blockIdx.x;
  int kc  = bid & 7;           // == XCD id
  int mT  = bid >> 3;          // 0..31
  int bRow = mT * 128;
  int kt0 = kc * 14;
  int i_start = min(max(0, kt0 - 48), 48);

  int tid = threadIdx.x, w = tid >> 6, l = tid & 63;
  int wm = (w >> 2) * 64, wn = (w & 3) * 64;
  int fr = l & 15, q = l >> 4;

  // stage Ssl: 128 rows x 16 s-cols [i_start, i_start+16)
#pragma unroll
  for (int r = 0; r < 2; ++r) {
    int p = r * 1024 + tid * 2;
    int row = p >> 4, col = p & 15;
    *(ushort2*)&Ssl[row * 18 + col] =
        *(const ushort2*)&Sb[(size_t)(bRow + row) * 64 + i_start + col];
  }

  // per-lane packed s_j (bf16 pairs) for outer-fragment synthesis
  uint4 sregu[4][2];
#pragma unroll
  for (int mi = 0; mi < 4; ++mi) {
    int grow = bRow + wm + mi * 16 + fr;
    sregu[mi][0] = *(const uint4*)&Sb[(size_t)grow * 64 + q * 8];
    sregu[mi][1] = *(const uint4*)&Sb[(size_t)grow * 64 + 32 + q * 8];
  }

  int r8 = l >> 3;
  int sg = ((l & 7) ^ r8) * 8;   // inverse-swizzled source slot

  auto stageA = [&](int bI, int kt) {   // 128x64: wave w rows [w*16, w*16+16)
    const ushort* src = Xb + (size_t)(bRow + w * 16 + r8) * KX + kt * 64 + sg;
#pragma unroll
    for (int c = 0; c < 2; ++c)
      gload16(src + (size_t)(c * 8) * KX, &As[bI][(w * 16 + c * 8) * 64]);
  };
  auto stageB = [&](int bI, int kt) {   // 256x64: wave w rows [w*32, w*32+32)
    const ushort* src = WBb + (size_t)(w * 32 + r8) * KTOT + kt * 64 + sg;
#pragma unroll
    for (int c = 0; c < 4; ++c)
      gload16(src + (size_t)(c * 8) * KTOT, &Bs[bI][(w * 32 + c * 8) * 64]);
  };

  f32x4 acc[4][4] = {};
  bf16x8 af[4][2], bfr[4][2];
  int buf = 0;

  if (kt0 < 48) stageA(0, kt0);
  stageB(0, kt0);
  __syncthreads();

#pragma unroll
  for (int tl = 0; tl < 14; ++tl) {
    int kt = kt0 + tl;
    if (tl + 1 < 14) {
      if (kt + 1 < 48) stageA(buf ^ 1, kt + 1);
      stageB(buf ^ 1, kt + 1);
    }

#pragma unroll
    for (int ni = 0; ni < 4; ++ni) {
      int col = wn + ni * 16 + fr;
#pragma unroll
      for (int ks = 0; ks < 2; ++ks) {
        int slot = (ks * 4 + q) ^ (col & 7);
        bfr[ni][ks] = *(const bf16x8*)&Bs[buf][col * 64 + slot * 8];
      }
    }
    if (kt < 48) {            // X region: fragments from LDS
#pragma unroll
      for (int mi = 0; mi < 4; ++mi) {
        int row = wm + mi * 16 + fr;
#pragma unroll
        for (int ks = 0; ks < 2; ++ks) {
          int slot = (ks * 4 + q) ^ (row & 7);
          af[mi][ks] = *(const bf16x8*)&As[buf][row * 64 + slot * 8];
        }
      }
    } else {                  // outer region: A[m][j] = s[m][i] * s[m][j]
      int iloc = kt - 48 - i_start;      // runtime, LDS index only
#pragma unroll
      for (int mi = 0; mi < 4; ++mi) {
        float si = b2f(Ssl[(wm + mi * 16 + fr) * 18 + iloc]);
#pragma unroll
        for (int ks = 0; ks < 2; ++ks) {
          uint4 uv = sregu[mi][ks];
          bf16x8 a;
          a[0] = (__bf16)(si * blo(uv.x)); a[1] = (__bf16)(si * bhi(uv.x));
          a[2] = (__bf16)(si * blo(uv.y)); a[3] = (__bf16)(si * bhi(uv.y));
          a[4] = (__bf16)(si * blo(uv.z)); a[5] = (__bf16)(si * bhi(uv.z));
          a[6] = (__bf16)(si * blo(uv.w)); a[7] = (__bf16)(si * bhi(uv.w));
          af[mi][ks] = a;
        }
      }
    }
#pragma unroll
    for (int ks = 0; ks < 2; ++ks)
#pragma unroll
      for (int mi = 0; mi < 4; ++mi)
#pragma unroll
        for (int ni = 0; ni < 4; ++ni)
          acc[mi][ni] = __builtin_amdgcn_mfma_f32_16x16x32_bf16(
              af[mi][ks], bfr[ni][ks], acc[mi][ni], 0, 0, 0);
    __syncthreads();
    buf ^= 1;
  }

  // epilogue: bf16 partial stores (halved HBM round-trip)
  ushort* Lpk = Lp + (size_t)kc * (B_ * D1_);
#pragma unroll
  for (int mi = 0; mi < 4; ++mi) {
    int row0 = bRow + wm + mi * 16 + q * 4;
#pragma unroll
    for (int ni = 0; ni < 4; ++ni) {
      int col = wn + ni * 16 + fr;
#pragma unroll
      for (int r = 0; r < 4; ++r)
        Lpk[(size_t)(row0 + r) * D1_ + col] = f2b(acc[mi][ni][r]);
    }
  }
}

// ============ K2: fused MLP (sum 8 bf16 partials + bias, l1+l2+head) ========
__global__ __launch_bounds__(256) void mlp_fused(
    const ushort* __restrict__ Lp, const float* __restrict__ dense,
    const ushort* __restrict__ W1b, const ushort* __restrict__ W2b,
    const float* __restrict__ bz, const float* __restrict__ bpi,
    const float* __restrict__ bpo, const float* __restrict__ B1v,
    const float* __restrict__ b1, const float* __restrict__ b2,
    const float* __restrict__ W3, const float* __restrict__ b3,
    float* __restrict__ out) {
  __shared__ ushort hs[16 * 264];
  __shared__ ushort h2s[16 * 136];
  __shared__ float bvs[256];
  int b0 = blockIdx.x * 16;
  int tid = threadIdx.x, w = tid >> 6, l = tid & 63;
  int row = l & 15, q = l >> 4;
  int wn = w * 64;

  bvs[tid] = bz[tid] + bpi[tid] + bpo[tid] + B1v[tid];
  __syncthreads();

  f32x4 acc1[4] = {};
  for (int kt = 0; kt < 9; ++kt) {
    int k0 = kt * 32 + q * 8;
    bf16x8 afr;
    if (kt < 8) {
      size_t base = (size_t)(b0 + row) * D1_ + k0;
      float s[8] = {0.f, 0.f, 0.f, 0.f, 0.f, 0.f, 0.f, 0.f};
#pragma unroll
      for (int p = 0; p < NKC; ++p) {
        uint4 u = *(const uint4*)&Lp[(size_t)p * (B_ * D1_) + base];
        s[0] += blo(u.x); s[1] += bhi(u.x);
        s[2] += blo(u.y); s[3] += bhi(u.y);
        s[4] += blo(u.z); s[5] += bhi(u.z);
        s[6] += blo(u.w); s[7] += bhi(u.w);
      }
      float4 bv0 = *(const float4*)&bvs[k0];
      float4 bv1 = *(const float4*)&bvs[k0 + 4];
      afr[0] = (__bf16)(s[0] + bv0.x); afr[1] = (__bf16)(s[1] + bv0.y);
      afr[2] = (__bf16)(s[2] + bv0.z); afr[3] = (__bf16)(s[3] + bv0.w);
      afr[4] = (__bf16)(s[4] + bv1.x); afr[5] = (__bf16)(s[5] + bv1.y);
      afr[6] = (__bf16)(s[6] + bv1.z); afr[7] = (__bf16)(s[7] + bv1.w);
    } else if (q < 2) {
      float4 u0 = *(const float4*)&dense[(size_t)(b0 + row) * DD_ + q * 8];
      float4 u1 = *(const float4*)&dense[(size_t)(b0 + row) * DD_ + q * 8 + 4];
      afr[0] = (__bf16)u0.x; afr[1] = (__bf16)u0.y; afr[2] = (__bf16)u0.z; afr[3] = (__bf16)u0.w;
      afr[4] = (__bf16)u1.x; afr[5] = (__bf16)u1.y; afr[6] = (__bf16)u1.z; afr[7] = (__bf16)u1.w;
    } else {
      afr = (bf16x8)(__bf16)0.f;
    }
#pragma unroll
    for (int ni = 0; ni < 4; ++ni) {
      bf16x8 bfr = *(const bf16x8*)&W1b[(size_t)(wn + ni * 16 + row) * 288 + k0];
      acc1[ni] = __builtin_amdgcn_mfma_f32_16x16x32_bf16(afr, bfr, acc1[ni], 0, 0, 0);
    }
  }
#pragma unroll
  for (int ni = 0; ni < 4; ++ni) {
    int col = wn + ni * 16 + row;
    float bias = b1[col];
#pragma unroll
    for (int r = 0; r < 4; ++r)
      hs[(q * 4 + r) * 264 + col] = f2b(tanhf(acc1[ni][r] + bias));
  }
  __syncthreads();

  int wn2 = w * 32;
  f32x4 acc2[2] = {};
  for (int kt = 0; kt < 8; ++kt) {
    int k0 = kt * 32 + q * 8;
    bf16x8 afr = *(const bf16x8*)&hs[row * 264 + k0];
#pragma unroll
    for (int ni = 0; ni < 2; ++ni) {
      bf16x8 bfr = *(const bf16x8*)&W2b[(size_t)(wn2 + ni * 16 + row) * 256 + k0];
      acc2[ni] = __builtin_amdgcn_mfma_f32_16x16x32_bf16(afr, bfr, acc2[ni], 0, 0, 0);
    }
  }
#pragma unroll
  for (int ni = 0; ni < 2; ++ni) {
    int col = wn2 + ni * 16 + row;
    float bias = b2[col];
#pragma unroll
    for (int r = 0; r < 4; ++r)
      h2s[(q * 4 + r) * 136 + col] = f2b(tanhf(acc2[ni][r] + bias));
  }
  __syncthreads();

  if (w == 0) {
    int rr = l >> 2, g = l & 3;
    float sum = 0.f;
#pragma unroll
    for (int jj = 0; jj < 32; ++jj) {
      int j = g * 32 + jj;
      sum += b2f(h2s[rr * 136 + j]) * W3[j];
    }
    sum += __shfl_xor(sum, 1, 64);
    sum += __shfl_xor(sum, 2, 64);
    if (g == 0) out[b0 + rr] = sum + b3[0];
  }
}

extern "C" void kernel_launch(void* const* d_in, const int* in_sizes, int n_in,
                              void* d_out, int out_size, void* d_ws, size_t ws_size,
                              hipStream_t stream) {
  const int*   sparse = (const int*)  d_in[0];
  const float* dense  = (const float*)d_in[1];
  const float* tables = (const float*)d_in[2];
  const float* Wz     = (const float*)d_in[3];
  const float* bz     = (const float*)d_in[4];
  const float* Wpi    = (const float*)d_in[5];
  const float* bpi    = (const float*)d_in[6];
  const float* Wpo    = (const float*)d_in[7];
  const float* bpo    = (const float*)d_in[8];
  const float* B1v    = (const float*)d_in[9];
  const float* W1     = (const float*)d_in[10];
  const float* b1     = (const float*)d_in[11];
  const float* W2     = (const float*)d_in[12];
  const float* b2     = (const float*)d_in[13];
  const float* W3     = (const float*)d_in[14];
  const float* b3     = (const float*)d_in[15];
  float* out = (float*)d_out;

  // ws layout (bytes), total ~46.4 MB
  char* ws = (char*)d_ws;
  ushort* Xb  = (ushort*)(ws);               // 4096*3072*2 = 25,165,824
  ushort* WBb = (ushort*)(ws + 25165824);    // 256*7168*2  =  3,670,016
  ushort* W1b = (ushort*)(ws + 28835840);    // 256*288*2   =    147,456
  ushort* W2b = (ushort*)(ws + 28983296);    // 128*256*2   =     65,536
  ushort* Sb  = (ushort*)(ws + 29048832);    // 4096*64*2   =    524,288
  ushort* Lp  = (ushort*)(ws + 29573120);    // 8*4096*256*2= 16,777,216

  prep_gather<<<dim3(1664), dim3(256), 0, stream>>>(
      Wz, Wpi, Wpo, W1, W2, sparse, tables, WBb, W1b, W2b, Xb, Sb);
  gemm_l1    <<<dim3(256),  dim3(512), 0, stream>>>(Xb, WBb, Sb, Lp);
  mlp_fused  <<<dim3(256),  dim3(256), 0, stream>>>(
      Lp, dense, W1b, W2b, bz, bpi, bpo, B1v, b1, b2, W3, b3, out);
}